// Round 1
// baseline (3915.094 us; speedup 1.0000x reference)
//
#include <hip/hip_runtime.h>
#include <cstdint>
#include <cstddef>

#define NQ 900
#define NC 91
#define NFLAT (NQ * NC)        // 81900
#define BS 8
#define PRE_TOPK 10000
#define TOPK 100
#define IOU_THR 0.7f
#define NTHREADS 512
#define SLOTS 20               // 512*20 = 10240 >= 10000
#define NB 1024                // histogram buckets per level
#define NLEVELS 5              // 5 * 10 bits = 50 >= 49-bit key
#define WS_STRIDE 81920        // per-batch stride in ws (uint32 elems)

// Key: prob in (0,1) => fp32 bits are monotone in value. 49-bit distinct key:
//   K = (probbits << 17) | (131071 - idx)   -> (prob desc, idx asc) == lax.top_k order
__device__ __forceinline__ unsigned int prob_bits(float x) {
    float p = 1.0f / (1.0f + expf(-x));
    return __float_as_uint(p);
}

extern "C" __global__ __launch_bounds__(NTHREADS, 1)
void NMSPostProcess_70463233458602_kernel(const float* __restrict__ logits,
                                          const float* __restrict__ pboxes,
                                          const float* __restrict__ tsizes,
                                          float* __restrict__ out,
                                          unsigned int* __restrict__ pbWs) {
    __shared__ int hist[NB];
    __shared__ int idxArr[NTHREADS * SLOTS];
    __shared__ unsigned long long sPrefix;
    __shared__ int sRem;
    __shared__ int sCnt;
    __shared__ unsigned long long sWaveRed[8];
    __shared__ float sWaveRedF[8];
    __shared__ unsigned long long sComb;
    __shared__ unsigned long long sFallback;
    __shared__ float sPick[5];   // ox1, oy1, ox2, oy2, area
    __shared__ float sBmax;

    const int b = blockIdx.x;
    const int tid = threadIdx.x;
    const int wid = tid >> 6;
    const int lane = tid & 63;
    const float* lg = logits + (size_t)b * NFLAT;
    unsigned int* pbRow = pbWs ? (pbWs + (size_t)b * WS_STRIDE) : nullptr;

    if (tid == 0) { sPrefix = 0ULL; sRem = PRE_TOPK; sCnt = 0; }
    __syncthreads();

    // ---------- Phase 1: exact top-10000 threshold via 5-level radix histogram ----------
    for (int level = 0; level < NLEVELS; ++level) {
        const int shift = 40 - 10 * level;
        hist[tid] = 0; hist[tid + 512] = 0;
        __syncthreads();
        const unsigned long long pref = sPrefix;
        for (int i = tid; i < NFLAT; i += NTHREADS) {
            unsigned int pb;
            if (pbRow) {
                if (level == 0) { pb = prob_bits(lg[i]); pbRow[i] = pb; }
                else            { pb = pbRow[i]; }
            } else {
                pb = prob_bits(lg[i]);
            }
            unsigned long long K = ((unsigned long long)pb << 17) |
                                   (unsigned long long)(131071 - i);
            if ((K >> (shift + 10)) == pref) {
                atomicAdd(&hist[(int)((K >> shift) & (NB - 1))], 1);
            }
        }
        __syncthreads();
        // save raw counts, then suffix-inclusive scan (Hillis-Steele) over 1024 buckets
        const int c0 = hist[tid], c1 = hist[tid + 512];
        for (int off = 1; off < NB; off <<= 1) {
            int t0 = (tid + off < NB) ? hist[tid + off] : 0;
            int t1 = (tid + 512 + off < NB) ? hist[tid + 512 + off] : 0;
            __syncthreads();
            hist[tid] += t0; hist[tid + 512] += t1;
            __syncthreads();
        }
        const int rem = sRem;
        const int si0 = hist[tid], si1 = hist[tid + 512];
        // unique crossing bucket: SI[b] >= rem and SI[b] - cnt[b] < rem
        if (si0 >= rem && si0 - c0 < rem) {
            sPrefix = (pref << 10) | (unsigned long long)tid;
            sRem = rem - (si0 - c0);
        }
        if (si1 >= rem && si1 - c1 < rem) {
            sPrefix = (pref << 10) | (unsigned long long)(tid + 512);
            sRem = rem - (si1 - c1);
        }
        __syncthreads();
    }
    const unsigned long long T = sPrefix;   // exact K of the 10000th-largest

    // ---------- Phase 2: compaction (order irrelevant; argmax uses K) ----------
    for (int i = tid; i < NFLAT; i += NTHREADS) {
        unsigned int pb = pbRow ? pbRow[i] : prob_bits(lg[i]);
        unsigned long long K = ((unsigned long long)pb << 17) |
                               (unsigned long long)(131071 - i);
        if (K >= T) {
            int pos = atomicAdd(&sCnt, 1);
            if (pos < NTHREADS * SLOTS) idxArr[pos] = i;
        }
    }
    __syncthreads();
    int cnt = sCnt; if (cnt > PRE_TOPK) cnt = PRE_TOPK;

    // ---------- Phase 3: load candidates into registers ----------
    const float img_h = tsizes[b * 2 + 0];
    const float img_w = tsizes[b * 2 + 1];
    float x1[SLOTS], y1[SLOTS], x2[SLOTS], y2[SLOTS], areaR[SLOTS];
    unsigned long long comb[SLOTS];
    int cidx[SLOTS];
    float localMax = -3.4e38f;
    #pragma unroll
    for (int s = 0; s < SLOTS; ++s) {
        const int p = s * NTHREADS + tid;
        comb[s] = 0ULL; cidx[s] = -1;
        x1[s] = 0.f; y1[s] = 0.f; x2[s] = 0.f; y2[s] = 0.f; areaR[s] = 0.f;
        if (p < cnt) {
            const int i = idxArr[p];
            cidx[s] = i;
            unsigned int pb = pbRow ? pbRow[i] : prob_bits(lg[i]);
            unsigned long long K = ((unsigned long long)pb << 17) |
                                   (unsigned long long)(131071 - i);
            comb[s] = (K << 14) | (unsigned long long)(tid * 32 + s);
            const int bi = i / NC;
            const float* bp = pboxes + (size_t)b * NQ * 4 + (size_t)bi * 4;
            const float cx = bp[0], cy = bp[1], w = bp[2], h = bp[3];
            const float bx1 = (cx - 0.5f * w) * img_w;
            const float by1 = (cy - 0.5f * h) * img_h;
            const float bx2 = (cx + 0.5f * w) * img_w;
            const float by2 = (cy + 0.5f * h) * img_h;
            x1[s] = bx1; y1[s] = by1; x2[s] = bx2; y2[s] = by2;
            localMax = fmaxf(localMax, fmaxf(fmaxf(bx1, by1), fmaxf(bx2, by2)));
        }
    }
    // bmax = boxes.max() over the gathered top-10000 (scaled xyxy)
    for (int off = 32; off >= 1; off >>= 1)
        localMax = fmaxf(localMax, __shfl_xor(localMax, off, 64));
    if (lane == 0) sWaveRedF[wid] = localMax;
    __syncthreads();
    if (tid == 0) {
        float m = sWaveRedF[0];
        for (int k = 1; k < 8; ++k) m = fmaxf(m, sWaveRedF[k]);
        sBmax = m;
    }
    __syncthreads();
    const float offc = sBmax + 1.0f;
    #pragma unroll
    for (int s = 0; s < SLOTS; ++s) {
        if (cidx[s] >= 0) {
            const int bi = cidx[s] / NC;
            const int l = cidx[s] - bi * NC;
            const float o = (float)l * offc;       // labels * (bmax + 1)
            x1[s] += o; y1[s] += o; x2[s] += o; y2[s] += o;
            areaR[s] = (x2[s] - x1[s]) * (y2[s] - y1[s]);   // area from obox, as ref
        }
    }
    __syncthreads();

    // ---------- Phase 4: NMS — 100 exact argmax+suppress iterations ----------
    float* outScores = out;            // [8][100]
    float* outLabels = out + BS * TOPK;        // [8][100] (as float)
    float* outBoxes  = out + 2 * BS * TOPK;    // [8][100][4]

    for (int t = 0; t < TOPK; ++t) {
        unsigned long long best = 0ULL;
        #pragma unroll
        for (int s = 0; s < SLOTS; ++s) best = (comb[s] > best) ? comb[s] : best;
        for (int off = 32; off >= 1; off >>= 1) {
            unsigned long long o = __shfl_xor(best, off, 64);
            best = (o > best) ? o : best;
        }
        if (lane == 0) sWaveRed[wid] = best;
        __syncthreads();
        if (tid == 0) {
            unsigned long long m = sWaveRed[0];
            for (int k = 1; k < 8; ++k) m = (sWaveRed[k] > m) ? sWaveRed[k] : m;
            if (t == 0) sFallback = m;              // global-max candidate
            if ((m >> 14) == 0ULL) m = sFallback;   // all -inf => ref picks index 0
            sComb = m;
        }
        __syncthreads();
        const unsigned long long w = sComb;
        const int wtid  = (int)((w >> 5) & 511);
        const int wslot = (int)(w & 31);
        if (tid == wtid) {
            float px1 = 0.f, py1 = 0.f, px2 = 0.f, py2 = 0.f, pa = 0.f;
            int i = 0;
            #pragma unroll
            for (int s = 0; s < SLOTS; ++s) {
                const bool sel = (s == wslot);
                px1 = sel ? x1[s] : px1; py1 = sel ? y1[s] : py1;
                px2 = sel ? x2[s] : px2; py2 = sel ? y2[s] : py2;
                pa  = sel ? areaR[s] : pa;
                i   = sel ? cidx[s]  : i;
            }
            sPick[0] = px1; sPick[1] = py1; sPick[2] = px2; sPick[3] = py2; sPick[4] = pa;
            // emit outputs for this keep
            unsigned int pb = pbRow ? pbRow[i] : prob_bits(lg[i]);
            const int bi = i / NC;
            const int l = i - bi * NC;
            const float* bp = pboxes + (size_t)b * NQ * 4 + (size_t)bi * 4;
            const float cx = bp[0], cy = bp[1], wd = bp[2], hh = bp[3];
            const int oi = b * TOPK + t;
            outScores[oi] = __uint_as_float(pb);
            outLabels[oi] = (float)l;
            outBoxes[oi * 4 + 0] = (cx - 0.5f * wd) * img_w;
            outBoxes[oi * 4 + 1] = (cy - 0.5f * hh) * img_h;
            outBoxes[oi * 4 + 2] = (cx + 0.5f * wd) * img_w;
            outBoxes[oi * 4 + 3] = (cy + 0.5f * hh) * img_h;
        }
        __syncthreads();
        const float px1 = sPick[0], py1 = sPick[1], px2 = sPick[2], py2 = sPick[3];
        const float pa = sPick[4];
        #pragma unroll
        for (int s = 0; s < SLOTS; ++s) {
            if (comb[s] != 0ULL) {
                float iw = fminf(px2, x2[s]) - fmaxf(px1, x1[s]);
                float ih = fminf(py2, y2[s]) - fmaxf(py1, y1[s]);
                iw = fmaxf(iw, 0.0f); ih = fmaxf(ih, 0.0f);
                const float inter = iw * ih;
                const float denom = pa + areaR[s] - inter;
                if (inter > IOU_THR * denom) comb[s] = 0ULL;   // self IoU=1 => suppressed
            }
        }
        __syncthreads();
    }
}

extern "C" void kernel_launch(void* const* d_in, const int* in_sizes, int n_in,
                              void* d_out, int out_size, void* d_ws, size_t ws_size,
                              hipStream_t stream) {
    const float* logits = (const float*)d_in[0];   // (8, 900, 91) fp32
    const float* pboxes = (const float*)d_in[1];   // (8, 900, 4) fp32
    const float* ts     = (const float*)d_in[2];   // (8, 2) fp32
    unsigned int* pb = nullptr;
    if (ws_size >= (size_t)BS * WS_STRIDE * sizeof(unsigned int))
        pb = (unsigned int*)d_ws;                  // cache sigmoid bits across passes
    hipLaunchKernelGGL(NMSPostProcess_70463233458602_kernel,
                       dim3(BS), dim3(NTHREADS), 0, stream,
                       logits, pboxes, ts, (float*)d_out, pb);
}

// Round 2
// 645.531 us; speedup vs baseline: 6.0649x; 6.0649x over previous
//
#include <hip/hip_runtime.h>
#include <cstdint>
#include <cstddef>

#define NQ 900
#define NC 91
#define NFLAT (NQ * NC)        // 81900
#define BS 8
#define PRE_TOPK 10000
#define TOPK 100
#define IOU_THR 0.7f
#define NT 1024
#define NWAVES (NT / 64)
#define SLOTS 10               // 1024*10 = 10240 >= 10000
#define HBINS 2048
#define CAP 4096
#define MAXLVL 4
#define WS_STRIDE 81920        // per-batch stride in ws (uint32 elems)

// prob in (0,1) => fp32 bits monotone in value. 49-bit distinct key:
//   K = (probbits << 17) | (131071 - idx)  == lax.top_k order (score desc, idx asc)
__device__ __forceinline__ unsigned int prob_bits(float x) {
    float p = 1.0f / (1.0f + expf(-x));
    return __float_as_uint(p);
}

__device__ __forceinline__ unsigned long long make_key(unsigned int pb, int i) {
    return ((unsigned long long)pb << 17) | (unsigned long long)(131071 - i);
}

// linear bucket on p; MUST be computed identically in every pass
__device__ __forceinline__ int bucket_of(float p, float lo, float invw) {
    int bk = (int)((p - lo) * invw);
    bk = bk < 0 ? 0 : bk;
    return bk > (HBINS - 1) ? (HBINS - 1) : bk;
}

extern "C" __global__ __launch_bounds__(NT)
void NMSPostProcess_70463233458602_kernel(const float* __restrict__ logits,
                                          const float* __restrict__ pboxes,
                                          const float* __restrict__ tsizes,
                                          float* __restrict__ out,
                                          unsigned int* __restrict__ pbWs) {
    __shared__ int hist[HBINS];                      // 8 KB
    __shared__ unsigned long long binKeys[CAP];      // 32 KB
    __shared__ int idxArr[NT * SLOTS];               // 40 KB
    __shared__ float sChLo[MAXLVL];
    __shared__ float sChInvw[MAXLVL];
    __shared__ int sChB[MAXLVL];
    __shared__ int sRem, sCount, sBin, sCnt, sTot;
    __shared__ unsigned long long sT;
    __shared__ unsigned long long sWaveRed[NWAVES];
    __shared__ float sWaveRedF[NWAVES];
    __shared__ int sWS[NWAVES];
    __shared__ unsigned long long sComb, sFallback;
    __shared__ float sBmax;

    const int b = blockIdx.x;
    const int tid = threadIdx.x;
    const int wid = tid >> 6;
    const int lane = tid & 63;
    const float* lg = logits + (size_t)b * NFLAT;
    unsigned int* pbRow = pbWs ? (pbWs + (size_t)b * WS_STRIDE) : nullptr;

    // ---------- Phase 1: exact top-10000 threshold ----------
    // level-0: 2048-bin linear histogram on p (uniform-ish -> no hot buckets)
    float curLo = 0.0f, curInvw = (float)HBINS;
    int rem = PRE_TOPK;
    int nlvl = 0;

    for (int lvl = 0; lvl < MAXLVL; ++lvl) {
        hist[tid] = 0; hist[tid + NT] = 0;
        __syncthreads();
        for (int i = tid; i < NFLAT; i += NT) {
            unsigned int pb;
            if (lvl == 0) {
                pb = prob_bits(lg[i]);
                if (pbRow) pbRow[i] = pb;
            } else {
                pb = pbRow ? pbRow[i] : prob_bits(lg[i]);
            }
            float p = __uint_as_float(pb);
            bool ok = true;
            for (int l = 0; l < lvl; ++l)
                ok &= (bucket_of(p, sChLo[l], sChInvw[l]) == sChB[l]);
            if (ok) atomicAdd(&hist[bucket_of(p, curLo, curInvw)], 1);
        }
        __syncthreads();
        const int raw0 = hist[tid], raw1 = hist[tid + NT];
        // suffix-inclusive scan over 2048 bins (count of elems in bins >= b)
        for (int off = 1; off < HBINS; off <<= 1) {
            int t0 = (tid + off < HBINS) ? hist[tid + off] : 0;
            int t1 = (tid + NT + off < HBINS) ? hist[tid + NT + off] : 0;
            __syncthreads();
            hist[tid] += t0; hist[tid + NT] += t1;
            __syncthreads();
        }
        const int si0 = hist[tid], si1 = hist[tid + NT];
        if (si0 >= rem && si0 - raw0 < rem) { sBin = tid;       sRem = rem - (si0 - raw0); sCount = raw0; }
        if (si1 >= rem && si1 - raw1 < rem) { sBin = tid + NT;  sRem = rem - (si1 - raw1); sCount = raw1; }
        __syncthreads();
        rem = sRem;
        const int B = sBin, cntB = sCount;
        if (tid == 0) { sChLo[lvl] = curLo; sChInvw[lvl] = curInvw; sChB[lvl] = B; }
        __syncthreads();
        nlvl = lvl + 1;
        if (cntB <= CAP || lvl == MAXLVL - 1) break;
        curLo = curLo + (float)B / curInvw;     // refine (rare path)
        curInvw = curInvw * (float)HBINS;
    }

    // collect the crossing bin's elements and rank-select the exact threshold key
    if (tid == 0) { sCnt = 0; sT = 1ULL; }
    __syncthreads();
    for (int i = tid; i < NFLAT; i += NT) {
        unsigned int pb = pbRow ? pbRow[i] : prob_bits(lg[i]);
        float p = __uint_as_float(pb);
        bool ok = true;
        for (int l = 0; l < nlvl; ++l)
            ok &= (bucket_of(p, sChLo[l], sChInvw[l]) == sChB[l]);
        if (ok) {
            int pos = atomicAdd(&sCnt, 1);
            if (pos < CAP) binKeys[pos] = make_key(pb, i);
        }
    }
    __syncthreads();
    const int m = sCnt < CAP ? sCnt : CAP;
    for (int j = tid; j < m; j += NT) {
        unsigned long long kj = binKeys[j];
        int r = 0;
        for (int q = 0; q < m; ++q) r += (binKeys[q] > kj) ? 1 : 0;
        if (r == rem - 1) sT = kj;      // unique: keys distinct
    }
    __syncthreads();
    const unsigned long long T = sT;    // exact K of the 10000th-largest

    // ---------- Phase 2: compaction via count + block scan (no hot atomics) ----------
    int myc = 0;
    for (int i = tid; i < NFLAT; i += NT) {
        unsigned int pb = pbRow ? pbRow[i] : prob_bits(lg[i]);
        myc += (make_key(pb, i) >= T) ? 1 : 0;
    }
    int v = myc;
    for (int off = 1; off < 64; off <<= 1) {
        int o = __shfl_up(v, off, 64);
        if (lane >= off) v += o;
    }
    if (lane == 63) sWS[wid] = v;
    __syncthreads();
    if (tid == 0) {
        int acc = 0;
        for (int w2 = 0; w2 < NWAVES; ++w2) { int tt = sWS[w2]; sWS[w2] = acc; acc += tt; }
        sTot = acc;
    }
    __syncthreads();
    int base = sWS[wid] + (v - myc);
    for (int i = tid; i < NFLAT; i += NT) {
        unsigned int pb = pbRow ? pbRow[i] : prob_bits(lg[i]);
        if (make_key(pb, i) >= T) { if (base < NT * SLOTS) idxArr[base] = i; ++base; }
    }
    __syncthreads();
    const int cnt = sTot < NT * SLOTS ? sTot : NT * SLOTS;

    // ---------- Phase 3: candidates -> registers (7 VGPRs/slot, no spill) ----------
    const float img_h = tsizes[b * 2 + 0];
    const float img_w = tsizes[b * 2 + 1];
    float x1[SLOTS], y1[SLOTS], x2[SLOTS], y2[SLOTS], areaR[SLOTS];
    unsigned long long comb[SLOTS];
    float localMax = -3.4e38f;
    #pragma unroll
    for (int s = 0; s < SLOTS; ++s) {
        const int p = s * NT + tid;
        comb[s] = 0ULL;
        x1[s] = 0.f; y1[s] = 0.f; x2[s] = 0.f; y2[s] = 0.f; areaR[s] = 0.f;
        if (p < cnt) {
            const int i = idxArr[p];
            unsigned int pb = pbRow ? pbRow[i] : prob_bits(lg[i]);
            comb[s] = make_key(pb, i);
            const int bi = i / NC;
            const float* bp = pboxes + (size_t)b * NQ * 4 + (size_t)bi * 4;
            const float cx = bp[0], cy = bp[1], w = bp[2], h = bp[3];
            const float bx1 = (cx - 0.5f * w) * img_w;
            const float by1 = (cy - 0.5f * h) * img_h;
            const float bx2 = (cx + 0.5f * w) * img_w;
            const float by2 = (cy + 0.5f * h) * img_h;
            x1[s] = bx1; y1[s] = by1; x2[s] = bx2; y2[s] = by2;
            localMax = fmaxf(localMax, fmaxf(fmaxf(bx1, by1), fmaxf(bx2, by2)));
        }
    }
    for (int off = 32; off >= 1; off >>= 1)
        localMax = fmaxf(localMax, __shfl_xor(localMax, off, 64));
    if (lane == 0) sWaveRedF[wid] = localMax;
    __syncthreads();
    if (tid == 0) {
        float mm = sWaveRedF[0];
        for (int k = 1; k < NWAVES; ++k) mm = fmaxf(mm, sWaveRedF[k]);
        sBmax = mm;
    }
    __syncthreads();
    const float offc = sBmax + 1.0f;     // boxes.max() + 1, per batch (matches ref)
    #pragma unroll
    for (int s = 0; s < SLOTS; ++s) {
        if (comb[s] != 0ULL) {
            const int i = 131071 - (int)(comb[s] & 0x1FFFFULL);
            const int bi = i / NC;
            const int l = i - bi * NC;
            const float o = (float)l * offc;
            x1[s] += o; y1[s] += o; x2[s] += o; y2[s] += o;
            areaR[s] = (x2[s] - x1[s]) * (y2[s] - y1[s]);
        }
    }
    __syncthreads();

    // ---------- Phase 4: NMS — 100 argmax+suppress iterations, register-resident ----------
    float* outScores = out;                    // [8][100]
    float* outLabels = out + BS * TOPK;        // [8][100] (as float)
    float* outBoxes  = out + 2 * BS * TOPK;    // [8][100][4]

    for (int t = 0; t < TOPK; ++t) {
        unsigned long long best = 0ULL;
        #pragma unroll
        for (int s = 0; s < SLOTS; ++s) best = (comb[s] > best) ? comb[s] : best;
        for (int off = 32; off >= 1; off >>= 1) {
            unsigned long long o = __shfl_xor(best, off, 64);
            best = (o > best) ? o : best;
        }
        if (lane == 0) sWaveRed[wid] = best;
        __syncthreads();
        if (tid == 0) {
            unsigned long long mm = sWaveRed[0];
            for (int k = 1; k < NWAVES; ++k) mm = (sWaveRed[k] > mm) ? sWaveRed[k] : mm;
            if (t == 0) sFallback = mm;            // global-max candidate
            if (mm == 0ULL) mm = sFallback;        // all -inf => ref argmax -> index 0
            sComb = mm;
        }
        __syncthreads();
        const unsigned long long w = sComb;
        // every thread recomputes the picked obox from the key (no winner-locate)
        const int i = 131071 - (int)(w & 0x1FFFFULL);
        const int bi = i / NC;
        const int l = i - bi * NC;
        const float* bp = pboxes + (size_t)b * NQ * 4 + (size_t)bi * 4;
        const float cx = bp[0], cy = bp[1], wd = bp[2], hh = bp[3];
        const float bx1 = (cx - 0.5f * wd) * img_w;
        const float by1 = (cy - 0.5f * hh) * img_h;
        const float bx2 = (cx + 0.5f * wd) * img_w;
        const float by2 = (cy + 0.5f * hh) * img_h;
        const float o = (float)l * offc;
        const float px1 = bx1 + o, py1 = by1 + o, px2 = bx2 + o, py2 = by2 + o;
        const float pa = (px2 - px1) * (py2 - py1);
        if (tid == 0) {
            const int oi = b * TOPK + t;
            outScores[oi] = __uint_as_float((unsigned int)(w >> 17));
            outLabels[oi] = (float)l;
            outBoxes[oi * 4 + 0] = bx1;
            outBoxes[oi * 4 + 1] = by1;
            outBoxes[oi * 4 + 2] = bx2;
            outBoxes[oi * 4 + 3] = by2;
        }
        #pragma unroll
        for (int s = 0; s < SLOTS; ++s) {
            if (comb[s] != 0ULL) {
                float iw = fminf(px2, x2[s]) - fmaxf(px1, x1[s]);
                float ih = fminf(py2, y2[s]) - fmaxf(py1, y1[s]);
                iw = fmaxf(iw, 0.0f); ih = fmaxf(ih, 0.0f);
                const float inter = iw * ih;
                const float denom = pa + areaR[s] - inter;
                if (inter > IOU_THR * denom) comb[s] = 0ULL;   // self IoU=1 -> dies
            }
        }
    }
}

extern "C" void kernel_launch(void* const* d_in, const int* in_sizes, int n_in,
                              void* d_out, int out_size, void* d_ws, size_t ws_size,
                              hipStream_t stream) {
    const float* logits = (const float*)d_in[0];   // (8, 900, 91) fp32
    const float* pboxes = (const float*)d_in[1];   // (8, 900, 4) fp32
    const float* ts     = (const float*)d_in[2];   // (8, 2) fp32
    unsigned int* pb = nullptr;
    if (ws_size >= (size_t)BS * WS_STRIDE * sizeof(unsigned int))
        pb = (unsigned int*)d_ws;                  // cache sigmoid bits across passes
    hipLaunchKernelGGL(NMSPostProcess_70463233458602_kernel,
                       dim3(BS), dim3(NT), 0, stream,
                       logits, pboxes, ts, (float*)d_out, pb);
}

// Round 3
// 123.769 us; speedup vs baseline: 31.6321x; 5.2156x over previous
//
#include <hip/hip_runtime.h>
#include <cstdint>
#include <cstddef>

#define NQ 900
#define NC 91
#define NFLAT (NQ * NC)        // 81900
#define NF4 (NFLAT / 4)        // 20475 (exact: 81900 % 4 == 0)
#define BS 8
#define PRE_TOPK 10000
#define TOPK 100
#define IOU_THR 0.7f
#define NT 1024
#define NWAVES (NT / 64)
#define HB 2048                // histogram bins on p (uniform-ish, ~40/bin)
#define BCAP 2048              // crossing-bin capacity (50x expected count)
#define SCAP 10240
#define WS_U32_STRIDE 81920    // per-batch pb stride (uint32)
#define WS_REQ ((size_t)BS * WS_U32_STRIDE * 4)

// prob in (0,1) => fp32 bits monotone. 49-bit distinct key:
//   K = (probbits << 17) | (131071 - idx)  == lax.top_k order (score desc, idx asc)
__device__ __forceinline__ unsigned int prob_bits(float x) {
    return __float_as_uint(1.0f / (1.0f + expf(-x)));
}
__device__ __forceinline__ unsigned long long make_key(unsigned int pb, int i) {
    return ((unsigned long long)pb << 17) | (unsigned long long)(131071 - i);
}
__device__ __forceinline__ int bucket_of(unsigned int pb) {
    float p = __uint_as_float(pb);
    int bk = (int)(p * (float)HB);
    bk = bk < 0 ? 0 : bk;
    return bk > (HB - 1) ? (HB - 1) : bk;
}

// ---------------- K1: chip-wide sigmoid -> ws (640 blocks) ----------------
extern "C" __global__ __launch_bounds__(256)
void k1_sigmoid(const float* __restrict__ logits, unsigned int* __restrict__ pbWs) {
    const int b = blockIdx.y;
    const int j = blockIdx.x * 256 + threadIdx.x;   // float4 index
    if (j >= NF4) return;
    const float4 v = ((const float4*)(logits + (size_t)b * NFLAT))[j];
    uint4 r;
    r.x = prob_bits(v.x); r.y = prob_bits(v.y);
    r.z = prob_bits(v.z); r.w = prob_bits(v.w);
    ((uint4*)(pbWs + (size_t)b * WS_U32_STRIDE))[j] = r;
}

__device__ __forceinline__ uint4 load_pb4(const unsigned int* pb, const float* lg, int j) {
    if (pb) return ((const uint4*)pb)[j];
    const float4 v = ((const float4*)lg)[j];
    uint4 r;
    r.x = prob_bits(v.x); r.y = prob_bits(v.y);
    r.z = prob_bits(v.z); r.w = prob_bits(v.w);
    return r;
}

// -------- K2: per-batch exact top-10000 counting-sort + sorted-scan NMS --------
extern "C" __global__ __launch_bounds__(NT)
void k2_select_nms(const float* __restrict__ logits,
                   const float* __restrict__ pboxes,
                   const float* __restrict__ tsizes,
                   float* __restrict__ out,
                   const unsigned int* __restrict__ pbWs) {
    __shared__ unsigned long long sKeys[SCAP];   // 80 KB: final sorted top-10000 keys
    __shared__ unsigned long long sBinB[BCAP];   // 16 KB: crossing-bin elements
    __shared__ int sHist[HB];                    // raw counts (preserved)
    __shared__ int sScan[HB];                    // suffix scan -> exclusive-above
    __shared__ int sCur[HB];                     // scatter cursors
    __shared__ float sKx1[TOPK], sKy1[TOPK], sKx2[TOPK], sKy2[TOPK], sKa[TOPK];
    __shared__ float sFirst[6];
    __shared__ float sRedF[NWAVES];
    __shared__ int sBinCnt, sB, sRem, sAbove, sKept;
    __shared__ float sBmax;

    const int b = blockIdx.x;
    const int tid = threadIdx.x;
    const int wid = tid >> 6, lane = tid & 63;
    const unsigned int* pb = pbWs ? (pbWs + (size_t)b * WS_U32_STRIDE) : nullptr;
    const float* lg = logits + (size_t)b * NFLAT;
    const float* bx = pboxes + (size_t)b * NQ * 4;
    const float img_h = tsizes[b * 2 + 0], img_w = tsizes[b * 2 + 1];

    // ---- pass 1: 2048-bin histogram on p ----
    sHist[tid] = 0; sHist[tid + NT] = 0;
    if (tid == 0) sBinCnt = 0;
    __syncthreads();
    for (int j = tid; j < NF4; j += NT) {
        const uint4 v = load_pb4(pb, lg, j);
        atomicAdd(&sHist[bucket_of(v.x)], 1);
        atomicAdd(&sHist[bucket_of(v.y)], 1);
        atomicAdd(&sHist[bucket_of(v.z)], 1);
        atomicAdd(&sHist[bucket_of(v.w)], 1);
    }
    __syncthreads();

    // ---- suffix-inclusive scan over 2048 bins ----
    sScan[tid] = sHist[tid]; sScan[tid + NT] = sHist[tid + NT];
    __syncthreads();
    for (int off = 1; off < HB; off <<= 1) {
        const int t0 = (tid + off < HB) ? sScan[tid + off] : 0;
        const int t1 = (tid + NT + off < HB) ? sScan[tid + NT + off] : 0;
        __syncthreads();
        sScan[tid] += t0; sScan[tid + NT] += t1;
        __syncthreads();
    }
    {   // crossing bin B: above(B) < 10000 <= above(B)+cnt(B); also exclusive-above + cursors
        const int si0 = sScan[tid], c0 = sHist[tid];
        const int si1 = sScan[tid + NT], c1 = sHist[tid + NT];
        if (si0 >= PRE_TOPK && si0 - c0 < PRE_TOPK) { sB = tid;      sAbove = si0 - c0; sRem = PRE_TOPK - (si0 - c0); }
        if (si1 >= PRE_TOPK && si1 - c1 < PRE_TOPK) { sB = tid + NT; sAbove = si1 - c1; sRem = PRE_TOPK - (si1 - c1); }
        sScan[tid] = si0 - c0;      sCur[tid] = si0 - c0;
        sScan[tid + NT] = si1 - c1; sCur[tid + NT] = si1 - c1;
    }
    __syncthreads();
    const int B = sB, above = sAbove, rem = sRem;

    // ---- pass 2: bucket-major scatter (buckets > B) + collect crossing bin ----
    for (int j = tid; j < NF4; j += NT) {
        const uint4 v = load_pb4(pb, lg, j);
        const unsigned int pv[4] = { v.x, v.y, v.z, v.w };
        #pragma unroll
        for (int q = 0; q < 4; ++q) {
            const int bk = bucket_of(pv[q]);
            if (bk > B) {
                const int pos = atomicAdd(&sCur[bk], 1);
                sKeys[pos] = make_key(pv[q], 4 * j + q);
            } else if (bk == B) {
                const int pos = atomicAdd(&sBinCnt, 1);
                if (pos < BCAP) sBinB[pos] = make_key(pv[q], 4 * j + q);
            }
        }
    }
    __syncthreads();

    // ---- exact rank-select inside crossing bin -> positions [above, 10000) ----
    int cntB = sBinCnt; if (cntB > BCAP) cntB = BCAP;
    for (int jj = tid; jj < cntB; jj += NT) {
        const unsigned long long kj = sBinB[jj];
        int r = 0;
        for (int q = 0; q < cntB; ++q) r += (sBinB[q] > kj) ? 1 : 0;
        if (r < rem) sKeys[above + r] = kj;
    }
    __syncthreads();

    // ---- exact in-bucket rank for positions [0, above) (keys distinct) ----
    unsigned long long myk[10]; int mypos[10]; int nmine = 0;
    for (int p = tid; p < above; p += NT) {
        const unsigned long long k = sKeys[p];
        const int bk = bucket_of((unsigned int)(k >> 17));
        const int s0 = sScan[bk], len = sHist[bk];
        int r = 0;
        for (int q = 0; q < len; ++q) r += (sKeys[s0 + q] > k) ? 1 : 0;
        myk[nmine] = k; mypos[nmine] = s0 + r; ++nmine;
    }
    __syncthreads();
    for (int q = 0; q < nmine; ++q) sKeys[mypos[q]] = myk[q];
    __syncthreads();

    // ---- bmax over the exact top-10000 gathered scaled boxes ----
    float lmax = -3.4e38f;
    for (int p = tid; p < PRE_TOPK; p += NT) {
        const int i = 131071 - (int)(sKeys[p] & 0x1FFFFULL);
        const int bi = i / NC;
        const float4 bb = ((const float4*)bx)[bi];
        const float x1 = (bb.x - 0.5f * bb.z) * img_w;
        const float y1 = (bb.y - 0.5f * bb.w) * img_h;
        const float x2 = (bb.x + 0.5f * bb.z) * img_w;
        const float y2 = (bb.y + 0.5f * bb.w) * img_h;
        lmax = fmaxf(lmax, fmaxf(fmaxf(x1, y1), fmaxf(x2, y2)));
    }
    for (int off = 32; off >= 1; off >>= 1)
        lmax = fmaxf(lmax, __shfl_xor(lmax, off, 64));
    if (lane == 0) sRedF[wid] = lmax;
    __syncthreads();
    if (tid == 0) {
        float mm = sRedF[0];
        for (int k = 1; k < NWAVES; ++k) mm = fmaxf(mm, sRedF[k]);
        sBmax = mm;
    }
    __syncthreads();
    const float offc = sBmax + 1.0f;   // labels * (boxes.max() + 1)

    // ---- sorted-scan NMS (wave 0 only; equivalent to ref's 100x argmax) ----
    if (wid == 0) {
        int kept = 0;
        for (int base = 0; base < PRE_TOPK && kept < TOPK; base += 64) {
            const int c = base + lane;
            const bool valid = c < PRE_TOPK;
            const unsigned long long k = valid ? sKeys[c] : 0ULL;
            int i = valid ? (131071 - (int)(k & 0x1FFFFULL)) : 0;
            const int bi = i / NC, l = i - bi * NC;
            const float4 bb = ((const float4*)bx)[bi];
            const float bx1 = (bb.x - 0.5f * bb.z) * img_w;
            const float by1 = (bb.y - 0.5f * bb.w) * img_h;
            const float bx2 = (bb.x + 0.5f * bb.z) * img_w;
            const float by2 = (bb.y + 0.5f * bb.w) * img_h;
            const float o = (float)l * offc;
            const float ox1 = bx1 + o, oy1 = by1 + o, ox2 = bx2 + o, oy2 = by2 + o;
            const float ar = (ox2 - ox1) * (oy2 - oy1);
            bool alive = valid;
            for (int jj = 0; jj < kept; ++jj) {       // vs all earlier keeps
                float iw = fminf(sKx2[jj], ox2) - fmaxf(sKx1[jj], ox1);
                float ih = fminf(sKy2[jj], oy2) - fmaxf(sKy1[jj], oy1);
                iw = fmaxf(iw, 0.f); ih = fmaxf(ih, 0.f);
                const float inter = iw * ih;
                if (inter > IOU_THR * (sKa[jj] + ar - inter)) alive = false;
            }
            unsigned long long mask = __ballot(alive);
            while (mask != 0ULL && kept < TOPK) {
                const int s = __ffsll((unsigned long long)mask) - 1;  // highest score alive
                const float px1 = __shfl(ox1, s, 64);
                const float py1 = __shfl(oy1, s, 64);
                const float px2 = __shfl(ox2, s, 64);
                const float py2 = __shfl(oy2, s, 64);
                const float pa  = __shfl(ar,  s, 64);
                if (lane == s) {
                    sKx1[kept] = ox1; sKy1[kept] = oy1; sKx2[kept] = ox2; sKy2[kept] = oy2; sKa[kept] = ar;
                    const int oi = b * TOPK + kept;
                    const float sc = __uint_as_float((unsigned int)(k >> 17));
                    out[oi] = sc;
                    out[BS * TOPK + oi] = (float)l;
                    out[2 * BS * TOPK + oi * 4 + 0] = bx1;
                    out[2 * BS * TOPK + oi * 4 + 1] = by1;
                    out[2 * BS * TOPK + oi * 4 + 2] = bx2;
                    out[2 * BS * TOPK + oi * 4 + 3] = by2;
                    if (kept == 0) { sFirst[0] = sc; sFirst[1] = (float)l;
                                     sFirst[2] = bx1; sFirst[3] = by1;
                                     sFirst[4] = bx2; sFirst[5] = by2; }
                }
                ++kept;
                if (alive) {   // suppress vs the new keep (self IoU=1 -> dies)
                    float iw = fminf(px2, ox2) - fmaxf(px1, ox1);
                    float ih = fminf(py2, oy2) - fmaxf(py1, oy1);
                    iw = fmaxf(iw, 0.f); ih = fmaxf(ih, 0.f);
                    const float inter = iw * ih;
                    if (inter > IOU_THR * (pa + ar - inter)) alive = false;
                }
                mask = __ballot(alive);
            }
        }
        if (lane == 0) sKept = kept;
    }
    __syncthreads();
    // exhaustion: ref's argmax over all -inf -> index 0 -> replicate row 0
    for (int t = sKept + tid; t < TOPK; t += NT) {
        const int oi = b * TOPK + t;
        out[oi] = sFirst[0];
        out[BS * TOPK + oi] = sFirst[1];
        out[2 * BS * TOPK + oi * 4 + 0] = sFirst[2];
        out[2 * BS * TOPK + oi * 4 + 1] = sFirst[3];
        out[2 * BS * TOPK + oi * 4 + 2] = sFirst[4];
        out[2 * BS * TOPK + oi * 4 + 3] = sFirst[5];
    }
}

extern "C" void kernel_launch(void* const* d_in, const int* in_sizes, int n_in,
                              void* d_out, int out_size, void* d_ws, size_t ws_size,
                              hipStream_t stream) {
    const float* logits = (const float*)d_in[0];   // (8, 900, 91) fp32
    const float* pboxes = (const float*)d_in[1];   // (8, 900, 4) fp32
    const float* ts     = (const float*)d_in[2];   // (8, 2) fp32
    unsigned int* pb = nullptr;
    if (ws_size >= WS_REQ) {
        pb = (unsigned int*)d_ws;
        hipLaunchKernelGGL(k1_sigmoid, dim3((NF4 + 255) / 256, BS), dim3(256), 0, stream,
                           logits, pb);
    }
    hipLaunchKernelGGL(k2_select_nms, dim3(BS), dim3(NT), 0, stream,
                       logits, pboxes, ts, (float*)d_out, pb);
}